// Round 6
// baseline (102.762 us; speedup 1.0000x reference)
//
#include <hip/hip_runtime.h>

// Problem constants (from reference): B=256, IN=1024, OUT=1024, fp32.
#define BB   256
#define IN_  1024
#define OUTN 1024

// Round-6: kill LDS bandwidth (rounds 3-5 were LDS-read-BW bound at ~8 B per
// element-op == ~40 us). New data flow:
//   * wave = 2 b-rows x 64 o (lane = o). x[b][i] is WAVE-UNIFORM -> scalar
//     (SGPR) loads straight from global; x never touches LDS or the LDS pipe.
//   * w staged in LDS (pre-clamped AND pre-scaled); one ds_read_b128 per lane
//     per 4i feeds BOTH b-rows -> 2 B/elem distinct-address LDS traffic.
// Tile: 8b x 64o per block (4 waves), full K=1024 per block (no atomics).
// Grid = (256/8)*(1024/64) = 512 blocks = 2 blocks/CU, 8 waves/CU.
#define TB   8
#define TO   64
#define KC   128          // i per LDS stage (8 stages)
#define NSTG (IN_ / KC)
#define PAD  4            // row stride 132 fl: same banking as r4/r5 (0 conflicts)

#define LOG2E 1.4426950408889634f

// Barrier draining only lgkmcnt (LDS/SMEM), NOT vmcnt: prefetched global
// loads stay in flight across the barrier.
__device__ __forceinline__ void lds_barrier() {
    asm volatile("s_waitcnt lgkmcnt(0)\n\ts_barrier" ::: "memory");
}

// leaky_clamp(v,0,1,0.1) == med3(v, 0.1*v, 0.9 + 0.1*v)  (3 instructions).
__device__ __forceinline__ float leaky_clamp01(float v) {
    return __builtin_amdgcn_fmed3f(v, 0.1f * v, fmaf(0.1f, v, 0.9f));
}

// Numerics: |tau*z| <= ~0.9 (x~N(0,1), aw in [-0.016,0.16], tau=exp(0)=1) ->
// NO max-subtraction pass. t = x * (tau*log2e*aw) [scale folded into staged
// w]; d = sum exp2(t), n = sum exp2(t)*t; s = n / (d * tau * log2e).
__global__ __launch_bounds__(256, 2)
void esm_fused_kernel(const float* __restrict__ x,
                      const float* __restrict__ w,
                      const float* __restrict__ log_tau,
                      float* __restrict__ out) {
    __shared__ float wls[TO][KC + PAD];   // 64 x 132 floats = 33.8 KB

    const int tid = threadIdx.x;
    const int bid = blockIdx.x;
    // o-tile in low bits: XCD-local blocks share few w tiles (L2 locality).
    const int ot = bid & 15;             // 0..15
    const int bt = bid >> 4;             // 0..31
    const int b0 = bt * TB;
    const int o0 = ot * TO;

    const float scale = __expf(log_tau[0]) * LOG2E;   // tau * log2(e)

    const int lane = tid & 63;                                 // o within tile
    const int wv   = __builtin_amdgcn_readfirstlane(tid >> 6); // wave 0..3
    // This wave's two b-rows; all x accesses below are wave-uniform -> the
    // compiler scalarizes them to s_load (SGPR operands into the VALU).
    const float* xr0 = x + (size_t)(b0 + 2 * wv) * IN_;
    const float* xr1 = xr0 + IN_;

    // Staging decode: f = tid + t*256 -> row = (tid>>5) + 8t, i4 = (tid&31)*4.
    // 32-lane clusters read 512 B contiguous (coalesced); LDS writes are
    // contiguous b128 (conflict-free).
    const int srow = tid >> 5;           // 0..7
    const int si4  = (tid & 31) << 2;    // 0..124

    // Prefetch stage 0 of w into registers (8 float4 = 32 VGPRs).
    float4 rw[8];
    #pragma unroll
    for (int t = 0; t < 8; ++t)
        rw[t] = *(const float4*)&w[(size_t)(o0 + srow + 8 * t) * IN_ + si4];

    // Two accumulator chains per cell for ILP; cells: (b0+2wv, o), (b0+2wv+1, o).
    float d0a = 0.f, d0b = 0.f, n0a = 0.f, n0b = 0.f;
    float d1a = 0.f, d1b = 0.f, n1a = 0.f, n1b = 0.f;

    #pragma unroll
    for (int s = 0; s < NSTG; ++s) {
        if (s) lds_barrier();   // stage s-1 readers done before overwrite
        // Store prefetched w to LDS: clamp AND pre-scale (x used raw).
        #pragma unroll
        for (int t = 0; t < 8; ++t) {
            const float4 v = rw[t];
            float4 o4;
            o4.x = leaky_clamp01(v.x) * scale;
            o4.y = leaky_clamp01(v.y) * scale;
            o4.z = leaky_clamp01(v.z) * scale;
            o4.w = leaky_clamp01(v.w) * scale;
            *(float4*)&wls[srow + 8 * t][si4] = o4;
        }
        // Issue next stage's loads BEFORE the barrier (stay in flight).
        if (s + 1 < NSTG) {
            const int gbase = (s + 1) * KC;
            #pragma unroll
            for (int t = 0; t < 8; ++t)
                rw[t] = *(const float4*)&w[(size_t)(o0 + srow + 8 * t) * IN_ + gbase + si4];
        }
        lds_barrier();          // LDS writes visible; prefetch stays in flight

        const int gi0 = s * KC;
        // Inner: per 4i, ONE ds_read_b128 (distinct rows, stride-132 banking,
        // measured 0 conflicts) + 2 uniform x float4 (SGPR, off the LDS pipe)
        // feed 8 element-ops: 8 mul + 8 exp + 4 add + 4 add + 8 fma.
        #pragma unroll 4
        for (int i = 0; i < KC; i += 4) {
            const float4 w4 = *(const float4*)&wls[lane][i];
            const float4 x0 = *(const float4*)(xr0 + gi0 + i);   // wave-uniform
            const float4 x1 = *(const float4*)(xr1 + gi0 + i);   // wave-uniform

            const float t00 = x0.x * w4.x, t01 = x0.y * w4.y;
            const float t02 = x0.z * w4.z, t03 = x0.w * w4.w;
            const float t10 = x1.x * w4.x, t11 = x1.y * w4.y;
            const float t12 = x1.z * w4.z, t13 = x1.w * w4.w;

            const float e00 = __builtin_amdgcn_exp2f(t00);
            const float e01 = __builtin_amdgcn_exp2f(t01);
            const float e02 = __builtin_amdgcn_exp2f(t02);
            const float e03 = __builtin_amdgcn_exp2f(t03);
            const float e10 = __builtin_amdgcn_exp2f(t10);
            const float e11 = __builtin_amdgcn_exp2f(t11);
            const float e12 = __builtin_amdgcn_exp2f(t12);
            const float e13 = __builtin_amdgcn_exp2f(t13);

            d0a += e00; d0b += e01; d0a += e02; d0b += e03;
            n0a = fmaf(e00, t00, n0a); n0b = fmaf(e01, t01, n0b);
            n0a = fmaf(e02, t02, n0a); n0b = fmaf(e03, t03, n0b);
            d1a += e10; d1b += e11; d1a += e12; d1b += e13;
            n1a = fmaf(e10, t10, n1a); n1b = fmaf(e11, t11, n1b);
            n1a = fmaf(e12, t12, n1a); n1b = fmaf(e13, t13, n1b);
        }
    }

    // Epilogue: s = n / (d * scale). Each wave writes 2 rows x 64 consecutive
    // floats (256 B, coalesced). 1 MB total.
    const size_t base = (size_t)(b0 + 2 * wv) * OUTN + o0 + lane;
    out[base]        = (n0a + n0b) / ((d0a + d0b) * scale);
    out[base + OUTN] = (n1a + n1b) / ((d1a + d1b) * scale);
}

extern "C" void kernel_launch(void* const* d_in, const int* in_sizes, int n_in,
                              void* d_out, int out_size, void* d_ws, size_t ws_size,
                              hipStream_t stream) {
    const float* x  = (const float*)d_in[0];   // (256, 1024)
    const float* w  = (const float*)d_in[1];   // (1024, 1024)
    const float* lt = (const float*)d_in[2];   // scalar log_tau
    float* out = (float*)d_out;                // (256, 1024)

    esm_fused_kernel<<<(BB / TB) * (OUTN / TO), 256, 0, stream>>>(x, w, lt, out);
}

// Round 7
// 100.958 us; speedup vs baseline: 1.0179x; 1.0179x over previous
//
#include <hip/hip_runtime.h>

// Problem constants (from reference): B=256, IN=1024, OUT=1024, fp32.
#define BB   256
#define IN_  1024
#define OUTN 1024

// Round-7: LDS-BW fix done RIGHT. r5 was LDS-bound (8 B/elem = 41 us, matches
// dur). r6's scalar-x loads poisoned lgkmcnt (s_load shares the counter with
// ds_read -> serialized inner loop). This round: 4x4 register micro-tile
// -> 2 B/elem LDS (10 us), row-major LDS (the layout measured at 0 conflicts
// in r3-r5), cells at stride 16 so 16-lane row reads land 2-way on banks.
// 64x64 (b,o) tile, NI=8 i-chunks of K=128 (ONE LDS stage, ONE barrier),
// grid = 4*16*8 = 512 blocks = 2 blocks/CU, 8 waves/CU. Partials -> plain
// coalesced stores into ws (16 MB streaming, NOT r2's contended atomics);
// tiny finalize kernel sums 8 chunks.
#define TBb  64
#define TOo  64
#define NI   8
#define KC   (IN_ / NI)   // 128
#define LSTR (KC + 4)     // 132 floats: 16B-aligned rows, proven 0-conflict

#define LOG2E 1.4426950408889634f

// leaky_clamp(v,0,1,0.1) == med3(v, 0.1*v, 0.9 + 0.1*v)  (3 instructions).
__device__ __forceinline__ float leaky_clamp01(float v) {
    return __builtin_amdgcn_fmed3f(v, 0.1f * v, fmaf(0.1f, v, 0.9f));
}

// Numerics: |tau*z| <= ~0.9 (x~N(0,1), aw in [-0.016,0.16], tau=exp(0)=1) ->
// NO max-subtraction pass. t = x * (tau*log2e*aw) [scale folded into staged
// w]; d = sum exp2(t), n = sum exp2(t)*t; s = n / (d * tau * log2e).
// Chunked partials are plain associative sums.
__global__ __launch_bounds__(256, 2)
void esm_partial_kernel(const float* __restrict__ x,
                        const float* __restrict__ w,
                        const float* __restrict__ log_tau,
                        float* __restrict__ dpart,
                        float* __restrict__ npart) {
    __shared__ float xs[TBb][LSTR];    // 33.8 KB, x staged raw
    __shared__ float wls[TOo][LSTR];   // 33.8 KB, w staged clamped*scale

    const int tid = threadIdx.x;
    const int bid = blockIdx.x;
    // ic,ot in low bits: XCD-local blocks share one 512 KB w i-slice (L2).
    const int ic = bid & 7;              // i-chunk 0..7
    const int ot = (bid >> 3) & 15;      // o tile  0..15
    const int bt = bid >> 7;             // b tile  0..3
    const int b0 = bt * TBb;
    const int o0 = ot * TOo;
    const int i0 = ic * KC;

    const float scale = __expf(log_tau[0]) * LOG2E;   // tau * log2(e)

    // Stage 64 rows x 128 i of x and w: 2048 f4 per array, 8 f4 per thread.
    // 32-lane clusters read 512 B contiguous (coalesced); LDS writes are the
    // r3-r5 pattern (measured SQ_LDS_BANK_CONFLICT = 0).
    const int srow = tid >> 5;           // 0..7 (+8 per t)
    const int si4  = (tid & 31) << 2;    // 0..124
    #pragma unroll
    for (int t = 0; t < 8; ++t) {
        const int row = srow + 8 * t;
        *(float4*)&xs[row][si4] =
            *(const float4*)&x[(size_t)(b0 + row) * IN_ + i0 + si4];
        const float4 v = *(const float4*)&w[(size_t)(o0 + row) * IN_ + i0 + si4];
        float4 wo;
        wo.x = leaky_clamp01(v.x) * scale;
        wo.y = leaky_clamp01(v.y) * scale;
        wo.z = leaky_clamp01(v.z) * scale;
        wo.w = leaky_clamp01(v.w) * scale;
        *(float4*)&wls[row][si4] = wo;
    }
    __syncthreads();   // once per block; vmcnt drain amortized over K=128

    // 16x16 thread grid; cells at STRIDE 16: b = b0+ty+16a, o = o0+tx+16c.
    // Row reads then step banks by LSTR mod 32 = 4 per lane -> 8 banks
    // 2-way (free). x reads are 4-addr broadcasts (free).
    const int tx = tid & 15;
    const int ty = tid >> 4;

    float dacc[4][4] = {{0.f}};
    float nacc[4][4] = {{0.f}};

    for (int i = 0; i < KC; i += 4) {   // no unroll pragma: ~2 KB body, I$-safe
        float4 xv[4], wv[4];
        #pragma unroll
        for (int a = 0; a < 4; ++a) xv[a] = *(const float4*)&xs[ty + 16 * a][i];
        #pragma unroll
        for (int c = 0; c < 4; ++c) wv[c] = *(const float4*)&wls[tx + 16 * c][i];
        #pragma unroll
        for (int a = 0; a < 4; ++a) {
            #pragma unroll
            for (int c = 0; c < 4; ++c) {
                const float t0 = xv[a].x * wv[c].x;
                const float t1 = xv[a].y * wv[c].y;
                const float t2 = xv[a].z * wv[c].z;
                const float t3 = xv[a].w * wv[c].w;
                const float e0 = __builtin_amdgcn_exp2f(t0);
                const float e1 = __builtin_amdgcn_exp2f(t1);
                const float e2 = __builtin_amdgcn_exp2f(t2);
                const float e3 = __builtin_amdgcn_exp2f(t3);
                dacc[a][c] += ((e0 + e1) + (e2 + e3));
                nacc[a][c] = fmaf(e0, t0, fmaf(e1, t1,
                             fmaf(e2, t2, fmaf(e3, t3, nacc[a][c]))));
            }
        }
    }

    // Plain coalesced partial stores (lanes: consecutive tx -> consecutive o).
    float* __restrict__ dp = dpart + (size_t)ic * BB * OUTN;
    float* __restrict__ np = npart + (size_t)ic * BB * OUTN;
    #pragma unroll
    for (int a = 0; a < 4; ++a) {
        const size_t rb = (size_t)(b0 + ty + 16 * a) * OUTN + o0 + tx;
        #pragma unroll
        for (int c = 0; c < 4; ++c) {
            dp[rb + 16 * c] = dacc[a][c];
            np[rb + 16 * c] = nacc[a][c];
        }
    }
}

__global__ __launch_bounds__(256)
void esm_finalize_kernel(const float* __restrict__ dpart,
                         const float* __restrict__ npart,
                         const float* __restrict__ log_tau,
                         float* __restrict__ out) {
    const int idx = blockIdx.x * 256 + threadIdx.x;   // float4 index
    const float inv = 1.0f / (__expf(log_tau[0]) * LOG2E);
    float4 ds = {0.f, 0.f, 0.f, 0.f}, ns = {0.f, 0.f, 0.f, 0.f};
    #pragma unroll
    for (int ic = 0; ic < NI; ++ic) {
        const float4 d4 = ((const float4*)dpart)[(size_t)ic * (BB * OUTN / 4) + idx];
        const float4 n4 = ((const float4*)npart)[(size_t)ic * (BB * OUTN / 4) + idx];
        ds.x += d4.x; ds.y += d4.y; ds.z += d4.z; ds.w += d4.w;
        ns.x += n4.x; ns.y += n4.y; ns.z += n4.z; ns.w += n4.w;
    }
    float4 o4;
    o4.x = ns.x / ds.x * inv;
    o4.y = ns.y / ds.y * inv;
    o4.z = ns.z / ds.z * inv;
    o4.w = ns.w / ds.w * inv;
    ((float4*)out)[idx] = o4;
}

extern "C" void kernel_launch(void* const* d_in, const int* in_sizes, int n_in,
                              void* d_out, int out_size, void* d_ws, size_t ws_size,
                              hipStream_t stream) {
    const float* x  = (const float*)d_in[0];   // (256, 1024)
    const float* w  = (const float*)d_in[1];   // (1024, 1024)
    const float* lt = (const float*)d_in[2];   // scalar log_tau
    float* out = (float*)d_out;                // (256, 1024)

    float* dpart = (float*)d_ws;                          // 8 MB
    float* npart = dpart + (size_t)NI * BB * OUTN;        // 8 MB

    // Every ws cell is overwritten by plain stores -> no memset needed.
    esm_partial_kernel<<<(BB / TBb) * (OUTN / TOo) * NI, 256, 0, stream>>>(
        x, w, lt, dpart, npart);
    esm_finalize_kernel<<<(BB * OUTN) / 1024, 256, 0, stream>>>(
        dpart, npart, lt, out);
}